// Round 2
// baseline (867.667 us; speedup 1.0000x reference)
//
#include <hip/hip_runtime.h>
#include <hip/hip_bf16.h>

typedef unsigned short u16;
typedef unsigned int u32;

#define LSEQ 256

// ---------------- ws float-offsets ----------------
constexpr int XW_F  = 0;        // [b][t][1024] fp32 (x@W + b), fwd
constexpr int XW_B  = 524288;   // bwd
constexpr int HF_O  = 1048576;  // hstep_f [s][b][256]
constexpr int HB_O  = 1179648;  // hstep_b [s][b][256] (s = step, t_orig = 255-s)
constexpr int UV_O  = 1310720;  // [mat 0..5][row 0..511][128] relu activations
constexpr int PEH_O = 1703936;  // [512]
constexpr int QEH_O = 1704448;  // [512]
constexpr int PHH_O = 1704960;  // [512][24]
constexpr int QHH_O = 1717248;
constexpr int PTT_O = 1729536;
constexpr int QTT_O = 1741824;
constexpr int TAG_O = 1754112;  // 16 u32 step tags
constexpr int DT_O  = 1754128;  // dtype flag as float: 1.0 = fp32 inputs, 0.0 = bf16
// converted-to-fp32 weights:
constexpr int CW_WF = 1754240;  // 262144
constexpr int CW_UF = 2016384;  // 262144
constexpr int CW_BF = 2278528;  // 1024
constexpr int CW_WB = 2279552;  // 262144
constexpr int CW_UB = 2541696;  // 262144
constexpr int CW_BB = 2803840;  // 1024
constexpr int HD0   = 2804864;  // per-head block
constexpr int HDS   = 167424;   // head stride
constexpr int HD1   = HD0 + HDS;
constexpr int HD2   = HD0 + 2 * HDS;
// within-head offsets: uW 0, ub 65536, vW 65664, vb 131200, uvW 131328,
// uvb 164096, clsW 164224, clsb 167296

__device__ __forceinline__ float b2f(u16 u) {
  u32 x = ((u32)u) << 16; float f;
  __builtin_memcpy(&f, &x, 4); return f;
}
__device__ __forceinline__ u16 f2b(float f) {
  u32 x; __builtin_memcpy(&x, &f, 4);
  u32 r = (x + 0x7fffu + ((x >> 16) & 1u)) >> 16;
  return (u16)r;
}
__device__ __forceinline__ float sigm(float x) { return 1.f / (1.f + __expf(-x)); }

// ---------------- k_detect: dtype probe + zero tags ----------------
__global__ __launch_bounds__(256) void k_detect(const void* __restrict__ etab,
                                                float* __restrict__ ws)
{
  __shared__ int cnt;
  const int tid = threadIdx.x;
  if (tid == 0) cnt = 0;
  __syncthreads();
  const u32 w = ((const u32*)etab)[tid];
  // low u16 viewed as bf16: |x| >= 2  <=>  exponent bit14 set.
  // fp32 storage: bit14 is a mantissa bit (~uniform) -> ~128/256 hits.
  // bf16 storage: low u16 is a ~N(0,0.05) weight -> 0 hits.
  if (w & 0x4000u) atomicAdd(&cnt, 1);
  __syncthreads();
  if (tid == 0) ws[DT_O] = (cnt >= 16) ? 1.0f : 0.0f;
  if (tid < 16) ((u32*)(ws + TAG_O))[tid] = 0u;
}

// ---------------- k_convert: normalize all weights to fp32 in ws ----------------
struct PtrPack { const void* p[30]; };

__global__ __launch_bounds__(256) void k_convert(PtrPack pk, float* __restrict__ ws)
{
  const int cnts[30] = {
    262144, 262144, 1024, 262144, 262144, 1024,
    65536, 128, 65536, 128, 32768, 128, 128, 1,
    65536, 128, 65536, 128, 32768, 128, 3072, 24,
    65536, 128, 65536, 128, 32768, 128, 3072, 24};
  const int dsts[30] = {
    CW_WF, CW_UF, CW_BF, CW_WB, CW_UB, CW_BB,
    HD0, HD0 + 65536, HD0 + 65664, HD0 + 131200, HD0 + 131328, HD0 + 164096, HD0 + 164224, HD0 + 167296,
    HD1, HD1 + 65536, HD1 + 65664, HD1 + 131200, HD1 + 131328, HD1 + 164096, HD1 + 164224, HD1 + 167296,
    HD2, HD2 + 65536, HD2 + 65664, HD2 + 131200, HD2 + 131328, HD2 + 164096, HD2 + 164224, HD2 + 167296};
  const int job = blockIdx.y;
  const int n = cnts[job];
  float* dst = ws + dsts[job];
  const void* src = pk.p[job];
  const bool f32m = ws[DT_O] > 0.5f;
  const int tid = threadIdx.x;
  if (f32m) {
    const float* s = (const float*)src;
    for (int i = blockIdx.x * 256 + tid; i < n; i += 128 * 256) dst[i] = s[i];
  } else {
    const u16* s = (const u16*)src;
    for (int i = blockIdx.x * 256 + tid; i < n; i += 128 * 256) dst[i] = b2f(s[i]);
  }
}

// ---------------- k_embed_xw: embeddings + x@W (+b), both dirs ----------------
__global__ __launch_bounds__(256) void k_embed_xw(
    const int* __restrict__ toks, const int* __restrict__ wrds,
    const void* __restrict__ etab, const void* __restrict__ wtab,
    float* __restrict__ ws)
{
  __shared__ float xs[2][256];
  const int tid = threadIdx.x, blk = blockIdx.x;
  const bool f32m = ws[DT_O] > 0.5f;
  for (int rr = 0; rr < 2; rr++) {
    const int row = blk * 2 + rr;
    const int id = toks[row], wid = wrds[row];
    float v;
    if (f32m) {
      v = (tid < 128) ? ((const float*)etab)[id * 128 + tid]
                      : ((const float*)wtab)[wid * 128 + (tid - 128)];
    } else {
      v = (tid < 128) ? b2f(((const u16*)etab)[id * 128 + tid])
                      : b2f(((const u16*)wtab)[wid * 128 + (tid - 128)]);
    }
    xs[rr][tid] = v;
  }
  __syncthreads();
  float aF[2][4] = {{0.f,0.f,0.f,0.f},{0.f,0.f,0.f,0.f}};
  float aB[2][4] = {{0.f,0.f,0.f,0.f},{0.f,0.f,0.f,0.f}};
  const float2* Wf2 = (const float2*)(ws + CW_WF);
  const float2* Wb2 = (const float2*)(ws + CW_WB);
  for (int k = 0; k < 256; k++) {
    const float x0 = xs[0][k], x1 = xs[1][k];
    float2 wa = Wf2[k * 512 + tid];
    float2 wb = Wf2[k * 512 + 256 + tid];
    aF[0][0] = fmaf(x0, wa.x, aF[0][0]); aF[0][1] = fmaf(x0, wa.y, aF[0][1]);
    aF[0][2] = fmaf(x0, wb.x, aF[0][2]); aF[0][3] = fmaf(x0, wb.y, aF[0][3]);
    aF[1][0] = fmaf(x1, wa.x, aF[1][0]); aF[1][1] = fmaf(x1, wa.y, aF[1][1]);
    aF[1][2] = fmaf(x1, wb.x, aF[1][2]); aF[1][3] = fmaf(x1, wb.y, aF[1][3]);
    wa = Wb2[k * 512 + tid];
    wb = Wb2[k * 512 + 256 + tid];
    aB[0][0] = fmaf(x0, wa.x, aB[0][0]); aB[0][1] = fmaf(x0, wa.y, aB[0][1]);
    aB[0][2] = fmaf(x0, wb.x, aB[0][2]); aB[0][3] = fmaf(x0, wb.y, aB[0][3]);
    aB[1][0] = fmaf(x1, wa.x, aB[1][0]); aB[1][1] = fmaf(x1, wa.y, aB[1][1]);
    aB[1][2] = fmaf(x1, wb.x, aB[1][2]); aB[1][3] = fmaf(x1, wb.y, aB[1][3]);
  }
  const int c0 = 2 * tid, c2 = 512 + 2 * tid;
  for (int rr = 0; rr < 2; rr++) {
    const int row = blk * 2 + rr;
    float* of = ws + XW_F + row * 1024;
    of[c0]   = aF[rr][0] + ws[CW_BF + c0];
    of[c0+1] = aF[rr][1] + ws[CW_BF + c0 + 1];
    of[c2]   = aF[rr][2] + ws[CW_BF + c2];
    of[c2+1] = aF[rr][3] + ws[CW_BF + c2 + 1];
    float* ob = ws + XW_B + row * 1024;
    ob[c0]   = aB[rr][0] + ws[CW_BB + c0];
    ob[c0+1] = aB[rr][1] + ws[CW_BB + c0 + 1];
    ob[c2]   = aB[rr][2] + ws[CW_BB + c2];
    ob[c2+1] = aB[rr][3] + ws[CW_BB + c2 + 1];
  }
}

// ---------------- k_lstm: recurrence, U resident in VGPRs ----------------
// 16 WGs: 8 per direction (independent tag groups). Each WG owns 32 hidden
// units (128 gate-cols). Thread (ksec=tid>>5, q=tid&31) holds U[k0..k0+32)
// x cols[4q..4q+3] in 32 float4 registers. h exchanged via agent-scope
// atomics + per-WG release/acquire tags.
__global__ __launch_bounds__(256, 1) void k_lstm(
    const int* __restrict__ toks, float* __restrict__ ws)
{
  __shared__ float2 hsh[256];      // (b0,b1) per k
  __shared__ float psum[8][256];   // [ksec][b*128 + c]
  __shared__ float zsh[256];       // [b*128 + c]
  const int tid = threadIdx.x;
  const int dir = blockIdx.x >> 3, chunk = blockIdx.x & 7, base = chunk * 32;
  const int q = tid & 31, ksec = tid >> 5, k0 = ksec * 32;
  float* hstep = ws + (dir ? HB_O : HF_O);
  const float* xw = ws + (dir ? XW_B : XW_F);
  const float* Ubase = ws + (dir ? CW_UB : CW_UF);
  u32* tag = (u32*)(ws + TAG_O);

  const int lc0 = 4 * q;
  const int gc0 = ((lc0 >> 5) << 8) + base + (lc0 & 31);
  float4 us[32];
#pragma unroll
  for (int j = 0; j < 32; j++)
    us[j] = *(const float4*)(Ubase + (k0 + j) * 1024 + gc0);

  const int gr = tid >> 5, gj = tid & 31;             // gate phase (tid<64)
  const int rb = tid >> 7, rc = tid & 127;            // reduce phase
  const int rgc = ((rc >> 5) << 8) + base + (rc & 31);
  float cReg = 0.f, hReg = 0.f;
  float xwreg = xw[(rb * 256 + (dir ? 255 : 0)) * 1024 + rgc];

  for (int s = 0; s < LSEQ; s++) {
    const int t = dir ? (LSEQ - 1 - s) : s;
    if (s && tid < 8) {
      while ((int)__hip_atomic_load(&tag[dir * 8 + tid], __ATOMIC_ACQUIRE,
                                    __HIP_MEMORY_SCOPE_AGENT) < s)
        __builtin_amdgcn_s_sleep(1);
    }
    __syncthreads();                                   // A
    if (s) {
      float b0 = __hip_atomic_load(hstep + (s - 1) * 512 + tid,
                                   __ATOMIC_RELAXED, __HIP_MEMORY_SCOPE_AGENT);
      float b1 = __hip_atomic_load(hstep + (s - 1) * 512 + 256 + tid,
                                   __ATOMIC_RELAXED, __HIP_MEMORY_SCOPE_AGENT);
      hsh[tid] = make_float2(b0, b1);
    } else {
      hsh[tid] = make_float2(0.f, 0.f);
    }
    __syncthreads();                                   // B
    float a00 = 0.f, a01 = 0.f, a02 = 0.f, a03 = 0.f;
    float a10 = 0.f, a11 = 0.f, a12 = 0.f, a13 = 0.f;
#pragma unroll
    for (int j = 0; j < 32; j++) {
      const float2 h = hsh[k0 + j];
      const float4 u = us[j];
      a00 = fmaf(h.x, u.x, a00); a01 = fmaf(h.x, u.y, a01);
      a02 = fmaf(h.x, u.z, a02); a03 = fmaf(h.x, u.w, a03);
      a10 = fmaf(h.y, u.x, a10); a11 = fmaf(h.y, u.y, a11);
      a12 = fmaf(h.y, u.z, a12); a13 = fmaf(h.y, u.w, a13);
    }
    *(float4*)&psum[ksec][lc0]       = make_float4(a00, a01, a02, a03);
    *(float4*)&psum[ksec][128 + lc0] = make_float4(a10, a11, a12, a13);
    __syncthreads();                                   // C
    {
      float z = xwreg;
#pragma unroll
      for (int ks = 0; ks < 8; ks++) z += psum[ks][rb * 128 + rc];
      zsh[rb * 128 + rc] = z;
    }
    __syncthreads();                                   // D
    if (tid < 64) {
      const float* zr = &zsh[gr * 128];
      const float zi = zr[gj], zf = zr[32 + gj], zg = zr[64 + gj], zo = zr[96 + gj];
      const float cn = sigm(zf) * cReg + sigm(zi) * tanhf(zg);
      const float hn = sigm(zo) * tanhf(cn);
      if (toks[gr * 256 + t] != 0) { cReg = cn; hReg = hn; }
      __hip_atomic_store(hstep + s * 512 + gr * 256 + base + gj, hReg,
                         __ATOMIC_RELAXED, __HIP_MEMORY_SCOPE_AGENT);
    }
    // prefetch next step's xw (independent of the barrier)
    const int t2 = dir ? (s < 255 ? 254 - s : 0) : (s < 255 ? s + 1 : 255);
    xwreg = xw[(rb * 256 + t2) * 1024 + rgc];
    if (tid == 0)
      __hip_atomic_store(&tag[dir * 8 + chunk], (u32)(s + 1),
                         __ATOMIC_RELEASE, __HIP_MEMORY_SCOPE_AGENT);
  }
}

// ---------------- k_uv: u,v = relu(enc@W + b), 6 matrices ----------------
__global__ __launch_bounds__(256) void k_uv(float* __restrict__ ws)
{
  __shared__ float encs[2][512];
  const int tid = threadIdx.x, blk = blockIdx.x;
  for (int i = tid; i < 1024; i += 256) {
    const int rr = i >> 9, h = i & 511;
    const int row = blk * 2 + rr, b = row >> 8, t = row & 255;
    encs[rr][h] = (h < 256)
        ? ws[HF_O + (t * 2 + b) * 256 + h]
        : ws[HB_O + ((255 - t) * 2 + b) * 256 + (h - 256)];
  }
  __syncthreads();
  const float* wp[3]; float bias[3]; int mats[3], cs[3];
#pragma unroll
  for (int g = 0; g < 3; g++) {
    const int colid = tid + (g << 8);
    mats[g] = colid >> 7; cs[g] = colid & 127;
    const int head = mats[g] >> 1, part = mats[g] & 1;
    wp[g]  = ws + HD0 + head * HDS + (part ? 65664 : 0) + cs[g];
    bias[g] = ws[HD0 + head * HDS + (part ? 131200 : 65536) + cs[g]];
  }
  float acc[3][2] = {{0.f,0.f},{0.f,0.f},{0.f,0.f}};
  for (int k = 0; k < 512; k++) {
    const float e0 = encs[0][k], e1 = encs[1][k];
#pragma unroll
    for (int g = 0; g < 3; g++) {
      const float w = wp[g][k * 128];
      acc[g][0] = fmaf(e0, w, acc[g][0]);
      acc[g][1] = fmaf(e1, w, acc[g][1]);
    }
  }
#pragma unroll
  for (int g = 0; g < 3; g++) {
    for (int rr = 0; rr < 2; rr++) {
      const int row = blk * 2 + rr;
      ws[UV_O + (mats[g] * 512 + row) * 128 + cs[g]] = fmaxf(acc[g][rr] + bias[g], 0.f);
    }
  }
}

// ---------------- k_pq: P=(u@Wuv1+buv)@Wc, Q=(v@Wuv2)@Wc ----------------
__global__ __launch_bounds__(128) void k_pq(float* __restrict__ ws)
{
  __shared__ float us[6][128];
  __shared__ float ash[3][128], qsh[3][128];
  const int row = blockIdx.x, tid = threadIdx.x;
  for (int i = tid; i < 768; i += 128) {
    const int mat = i >> 7, e = i & 127;
    us[mat][e] = ws[UV_O + (mat * 512 + row) * 128 + e];
  }
  __syncthreads();
#pragma unroll
  for (int hd = 0; hd < 3; hd++) {
    const float* W = ws + HD0 + hd * HDS + 131328;
    float a = 0.f, qv = 0.f;
    for (int k = 0; k < 128; k++) {
      a  = fmaf(us[2 * hd][k],     W[k * 128 + tid], a);
      qv = fmaf(us[2 * hd + 1][k], W[(128 + k) * 128 + tid], qv);
    }
    ash[hd][tid] = a + ws[HD0 + hd * HDS + 164096 + tid];  // fold buv into P
    qsh[hd][tid] = qv;
  }
  __syncthreads();
  if (tid < 98) {
    const float* src; float* dst; const float* Wc; int o, nout;
    if (tid < 2) {
      Wc = ws + HD0 + 164224; nout = 1; o = 0;
      src = (tid == 0) ? ash[0] : qsh[0];
      dst = ws + ((tid == 0) ? PEH_O : QEH_O) + row;
    } else if (tid < 50) {
      Wc = ws + HD1 + 164224; nout = 24;
      if (tid < 26) { o = tid - 2;  src = ash[1]; dst = ws + PHH_O + row * 24 + o; }
      else          { o = tid - 26; src = qsh[1]; dst = ws + QHH_O + row * 24 + o; }
    } else {
      Wc = ws + HD2 + 164224; nout = 24;
      if (tid < 74) { o = tid - 50; src = ash[2]; dst = ws + PTT_O + row * 24 + o; }
      else          { o = tid - 74; src = qsh[2]; dst = ws + QTT_O + row * 24 + o; }
    }
    float acc = 0.f;
    for (int e = 0; e < 128; e++) acc = fmaf(src[e], Wc[e * nout + o], acc);
    *dst = acc;
  }
}

// ---------------- k_out: out[b,i,j] = act(P[b,j] + Q[b,i] + bc) ----------------
__global__ __launch_bounds__(256) void k_out(const float* __restrict__ ws,
                                             void* __restrict__ outv)
{
  __shared__ float qh[24], qt[24];
  __shared__ float qe_s;
  __shared__ u32 sh[3072], st[3072];
  const bool f32m = ws[DT_O] > 0.5f;
  const int bi = blockIdx.x, b = bi >> 8, i = bi & 255;
  const int j = threadIdx.x;
  if (j < 24)       qh[j] = ws[QHH_O + (b * 256 + i) * 24 + j] + ws[HD1 + 167296 + j];
  else if (j < 48)  qt[j - 24] = ws[QTT_O + (b * 256 + i) * 24 + (j - 24)] + ws[HD2 + 167296 + (j - 24)];
  else if (j == 48) qe_s = ws[QEH_O + b * 256 + i] + ws[HD0 + 167296];
  __syncthreads();
  {
    float v = ws[PEH_O + b * 256 + j] + qe_s;
    v = 1.f / (1.f + __expf(-v));
    if (f32m) ((float*)outv)[(b * 256 + i) * 256 + j] = v;
    else      ((u16*)outv)[(b * 256 + i) * 256 + j] = f2b(v);
  }
  float p[24];
  {
    const float* pp = ws + PHH_O + (b * 256 + j) * 24;
    float mx = -1e30f;
#pragma unroll
    for (int o = 0; o < 24; o++) { p[o] = pp[o] + qh[o]; mx = fmaxf(mx, p[o]); }
    float ssum = 0.f;
#pragma unroll
    for (int o = 0; o < 24; o++) { p[o] = __expf(p[o] - mx); ssum += p[o]; }
    const float inv = 1.f / ssum;
    if (f32m) {
      float* dst = (float*)outv + 131072 + (size_t)(bi * 256 + j) * 24;
#pragma unroll
      for (int m = 0; m < 6; m++)
        ((float4*)dst)[m] = make_float4(p[4*m]*inv, p[4*m+1]*inv, p[4*m+2]*inv, p[4*m+3]*inv);
    } else {
#pragma unroll
      for (int m = 0; m < 12; m++)
        sh[j * 12 + m] = ((u32)f2b(p[2*m+1] * inv) << 16) | (u32)f2b(p[2*m] * inv);
    }
  }
  {
    const float* pp = ws + PTT_O + (b * 256 + j) * 24;
    float mx = -1e30f;
#pragma unroll
    for (int o = 0; o < 24; o++) { p[o] = pp[o] + qt[o]; mx = fmaxf(mx, p[o]); }
    float ssum = 0.f;
#pragma unroll
    for (int o = 0; o < 24; o++) { p[o] = __expf(p[o] - mx); ssum += p[o]; }
    const float inv = 1.f / ssum;
    if (f32m) {
      float* dst = (float*)outv + 3276800 + (size_t)(bi * 256 + j) * 24;
#pragma unroll
      for (int m = 0; m < 6; m++)
        ((float4*)dst)[m] = make_float4(p[4*m]*inv, p[4*m+1]*inv, p[4*m+2]*inv, p[4*m+3]*inv);
    } else {
#pragma unroll
      for (int m = 0; m < 12; m++)
        st[j * 12 + m] = ((u32)f2b(p[2*m+1] * inv) << 16) | (u32)f2b(p[2*m] * inv);
    }
  }
  __syncthreads();
  if (!f32m) {
    u32* outu = (u32*)outv;
    const int baseH = 65536 + bi * 3072;     // eh = elems [0,131072)
    const int baseT = 1638400 + bi * 3072;   // tt starts at elem 3276800
#pragma unroll
    for (int m = 0; m < 12; m++) {
      outu[baseH + j + 256 * m] = sh[j + 256 * m];
      outu[baseT + j + 256 * m] = st[j + 256 * m];
    }
  }
}

extern "C" void kernel_launch(void* const* d_in, const int* in_sizes, int n_in,
                              void* d_out, int out_size, void* d_ws, size_t ws_size,
                              hipStream_t stream) {
  const int* toks = (const int*)d_in[0];
  const int* wrds = (const int*)d_in[1];
  float* ws = (float*)d_ws;

  k_detect<<<dim3(1), dim3(256), 0, stream>>>(d_in[3], ws);

  PtrPack pk;
  // Wf, Uf, bf, Wb, Ub, bb
  pk.p[0] = d_in[5]; pk.p[1] = d_in[6]; pk.p[2] = d_in[7];
  pk.p[3] = d_in[8]; pk.p[4] = d_in[9]; pk.p[5] = d_in[10];
  // per head: uW, ub, vW, vb, uvW, uvb, clsW, clsb
  for (int h = 0; h < 3; h++)
    for (int a = 0; a < 8; a++)
      pk.p[6 + h * 8 + a] = d_in[11 + h * 8 + a];
  k_convert<<<dim3(128, 30), dim3(256), 0, stream>>>(pk, ws);

  k_embed_xw<<<dim3(256), dim3(256), 0, stream>>>(toks, wrds, d_in[3], d_in[4], ws);
  k_lstm<<<dim3(16), dim3(256), 0, stream>>>(toks, ws);
  k_uv<<<dim3(256), dim3(256), 0, stream>>>(ws);
  k_pq<<<dim3(512), dim3(128), 0, stream>>>(ws);
  k_out<<<dim3(512), dim3(256), 0, stream>>>(ws, d_out);
}

// Round 3
// 807.224 us; speedup vs baseline: 1.0749x; 1.0749x over previous
//
#include <hip/hip_runtime.h>
#include <hip/hip_bf16.h>

typedef unsigned short u16;
typedef unsigned int u32;

#define LSEQ 256

// ---------------- ws float-offsets ----------------
constexpr int XW_F  = 0;        // [b][t][1024] fp32 (x@W + b), fwd
constexpr int XW_B  = 524288;   // bwd
constexpr int HF_O  = 1048576;  // hstep_f [s][b][256]
constexpr int HB_O  = 1179648;  // hstep_b [s][b][256] (s = step, t_orig = 255-s)
constexpr int UV_O  = 1310720;  // [mat 0..5][row 0..511][128] relu activations
constexpr int PEH_O = 1703936;  // [512]
constexpr int QEH_O = 1704448;  // [512]
constexpr int PHH_O = 1704960;  // [512][24]
constexpr int QHH_O = 1717248;
constexpr int PTT_O = 1729536;
constexpr int QTT_O = 1741824;
constexpr int DT_O  = 1754128;  // dtype flag as float: 1.0 = fp32 inputs, 0.0 = bf16
// converted-to-fp32 weights:
constexpr int CW_WF = 1754240;  // 262144
constexpr int CW_UF = 2016384;  // 262144
constexpr int CW_BF = 2278528;  // 1024
constexpr int CW_WB = 2279552;  // 262144
constexpr int CW_UB = 2541696;  // 262144
constexpr int CW_BB = 2803840;  // 1024
constexpr int HD0   = 2804864;  // per-head block
constexpr int HDS   = 167424;   // head stride
constexpr int HD1   = HD0 + HDS;
constexpr int HD2   = HD0 + 2 * HDS;
// within-head offsets: uW 0, ub 65536, vW 65664, vb 131200, uvW 131328,
// uvb 164096, clsW 164224, clsb 167296

__device__ __forceinline__ float b2f(u16 u) {
  u32 x = ((u32)u) << 16; float f;
  __builtin_memcpy(&f, &x, 4); return f;
}
__device__ __forceinline__ u16 f2b(float f) {
  u32 x; __builtin_memcpy(&x, &f, 4);
  u32 r = (x + 0x7fffu + ((x >> 16) & 1u)) >> 16;
  return (u16)r;
}
__device__ __forceinline__ float qnan() {
  u32 x = 0x7FC00000u; float f; __builtin_memcpy(&f, &x, 4); return f;
}
__device__ __forceinline__ float sigm(float x) { return 1.f / (1.f + __expf(-x)); }
__device__ __forceinline__ float aload(float* p) {
  return __hip_atomic_load(p, __ATOMIC_RELAXED, __HIP_MEMORY_SCOPE_AGENT);
}
__device__ __forceinline__ void astore(float* p, float v) {
  __hip_atomic_store(p, v, __ATOMIC_RELAXED, __HIP_MEMORY_SCOPE_AGENT);
}

// ---------------- k_detect: dtype probe ----------------
__global__ __launch_bounds__(256) void k_detect(const void* __restrict__ etab,
                                                float* __restrict__ ws)
{
  __shared__ int cnt;
  const int tid = threadIdx.x;
  if (tid == 0) cnt = 0;
  __syncthreads();
  const u32 w = ((const u32*)etab)[tid];
  // low u16 viewed as bf16: |x| >= 2 <=> bit14 set. fp32 storage: mantissa
  // bit (~uniform) -> ~128/256 hits. bf16 storage: small weight -> 0 hits.
  if (w & 0x4000u) atomicAdd(&cnt, 1);
  __syncthreads();
  if (tid == 0) ws[DT_O] = (cnt >= 16) ? 1.0f : 0.0f;
}

// ---------------- k_convert: normalize all weights to fp32 in ws ----------------
struct PtrPack { const void* p[30]; };

__global__ __launch_bounds__(256) void k_convert(PtrPack pk, float* __restrict__ ws)
{
  const int cnts[30] = {
    262144, 262144, 1024, 262144, 262144, 1024,
    65536, 128, 65536, 128, 32768, 128, 128, 1,
    65536, 128, 65536, 128, 32768, 128, 3072, 24,
    65536, 128, 65536, 128, 32768, 128, 3072, 24};
  const int dsts[30] = {
    CW_WF, CW_UF, CW_BF, CW_WB, CW_UB, CW_BB,
    HD0, HD0 + 65536, HD0 + 65664, HD0 + 131200, HD0 + 131328, HD0 + 164096, HD0 + 164224, HD0 + 167296,
    HD1, HD1 + 65536, HD1 + 65664, HD1 + 131200, HD1 + 131328, HD1 + 164096, HD1 + 164224, HD1 + 167296,
    HD2, HD2 + 65536, HD2 + 65664, HD2 + 131200, HD2 + 131328, HD2 + 164096, HD2 + 164224, HD2 + 167296};
  const int job = blockIdx.y;
  const int n = cnts[job];
  float* dst = ws + dsts[job];
  const void* src = pk.p[job];
  const bool f32m = ws[DT_O] > 0.5f;
  const int tid = threadIdx.x;
  if (f32m) {
    const float* s = (const float*)src;
    for (int i = blockIdx.x * 256 + tid; i < n; i += 128 * 256) dst[i] = s[i];
  } else {
    const u16* s = (const u16*)src;
    for (int i = blockIdx.x * 256 + tid; i < n; i += 128 * 256) dst[i] = b2f(s[i]);
  }
}

// ---------------- k_embed_xw: sentinel-init hstep + embeddings + x@W (+b) ----------------
// grid 128, 4 rows/block (halves the W stream vs 2 rows/block)
__global__ __launch_bounds__(256) void k_embed_xw(
    const int* __restrict__ toks, const int* __restrict__ wrds,
    const void* __restrict__ etab, const void* __restrict__ wtab,
    float* __restrict__ ws)
{
  __shared__ float xs[4][256];
  const int tid = threadIdx.x, blk = blockIdx.x;
  // qNaN-sentinel init of hstep (HF_O..HB_O+131072 contiguous, 262144 floats).
  // MUST be L2-bypassing atomic stores: a plain store would leave a dirty
  // sentinel line in some XCD L2 that could be written back to L3 AFTER the
  // real h values land there.
  {
    float* hz = ws + HF_O + (blk * 256 + tid) * 8;
    const float nv = qnan();
#pragma unroll
    for (int m = 0; m < 8; m++) astore(hz + m, nv);
  }
  const bool f32m = ws[DT_O] > 0.5f;
  for (int rr = 0; rr < 4; rr++) {
    const int row = blk * 4 + rr;
    const int id = toks[row], wid = wrds[row];
    float v;
    if (f32m) {
      v = (tid < 128) ? ((const float*)etab)[id * 128 + tid]
                      : ((const float*)wtab)[wid * 128 + (tid - 128)];
    } else {
      v = (tid < 128) ? b2f(((const u16*)etab)[id * 128 + tid])
                      : b2f(((const u16*)wtab)[wid * 128 + (tid - 128)]);
    }
    xs[rr][tid] = v;
  }
  __syncthreads();
  float aF[4][4], aB[4][4];
#pragma unroll
  for (int rr = 0; rr < 4; rr++)
#pragma unroll
    for (int c = 0; c < 4; c++) { aF[rr][c] = 0.f; aB[rr][c] = 0.f; }
  const float2* Wf2 = (const float2*)(ws + CW_WF);
  const float2* Wb2 = (const float2*)(ws + CW_WB);
  for (int k = 0; k < 256; k++) {
    const float2 wfa = Wf2[k * 512 + tid];
    const float2 wfb = Wf2[k * 512 + 256 + tid];
    const float2 wba = Wb2[k * 512 + tid];
    const float2 wbb = Wb2[k * 512 + 256 + tid];
#pragma unroll
    for (int rr = 0; rr < 4; rr++) {
      const float x = xs[rr][k];
      aF[rr][0] = fmaf(x, wfa.x, aF[rr][0]); aF[rr][1] = fmaf(x, wfa.y, aF[rr][1]);
      aF[rr][2] = fmaf(x, wfb.x, aF[rr][2]); aF[rr][3] = fmaf(x, wfb.y, aF[rr][3]);
      aB[rr][0] = fmaf(x, wba.x, aB[rr][0]); aB[rr][1] = fmaf(x, wba.y, aB[rr][1]);
      aB[rr][2] = fmaf(x, wbb.x, aB[rr][2]); aB[rr][3] = fmaf(x, wbb.y, aB[rr][3]);
    }
  }
  const int c0 = 2 * tid, c2 = 512 + 2 * tid;
#pragma unroll
  for (int rr = 0; rr < 4; rr++) {
    const int row = blk * 4 + rr;
    float* of = ws + XW_F + row * 1024;
    of[c0]   = aF[rr][0] + ws[CW_BF + c0];
    of[c0+1] = aF[rr][1] + ws[CW_BF + c0 + 1];
    of[c2]   = aF[rr][2] + ws[CW_BF + c2];
    of[c2+1] = aF[rr][3] + ws[CW_BF + c2 + 1];
    float* ob = ws + XW_B + row * 1024;
    ob[c0]   = aB[rr][0] + ws[CW_BB + c0];
    ob[c0+1] = aB[rr][1] + ws[CW_BB + c0 + 1];
    ob[c2]   = aB[rr][2] + ws[CW_BB + c2];
    ob[c2+1] = aB[rr][3] + ws[CW_BB + c2 + 1];
  }
}

// ---------------- k_lstm: recurrence, U in VGPRs, NaN-sentinel data sync ----------------
// 16 WGs: 8 per direction. Each WG owns 32 hidden units (128 gate-cols).
// h exchanged through L3 via agent-scope relaxed atomics; consumers poll the
// h words directly (qNaN sentinel) — no tags, no fences, ~2 L3 hops/step.
__global__ __launch_bounds__(256, 1) void k_lstm(
    const int* __restrict__ toks, float* __restrict__ ws)
{
  __shared__ float2 hsh[256];      // (b0,b1) per k
  __shared__ float psum[8][256];   // [ksec][b*128 + c]
  __shared__ float zsh[256];       // [b*128 + c]
  const int tid = threadIdx.x;
  const int dir = blockIdx.x >> 3, chunk = blockIdx.x & 7, base = chunk * 32;
  const int q = tid & 31, ksec = tid >> 5, k0 = ksec * 32;
  float* hstep = ws + (dir ? HB_O : HF_O);
  const float* xw = ws + (dir ? XW_B : XW_F);
  const float* Ubase = ws + (dir ? CW_UB : CW_UF);

  const int lc0 = 4 * q;
  const int gc0 = ((lc0 >> 5) << 8) + base + (lc0 & 31);
  float4 us[32];
#pragma unroll
  for (int j = 0; j < 32; j++)
    us[j] = *(const float4*)(Ubase + (k0 + j) * 1024 + gc0);

  const int gr = tid >> 5, gj = tid & 31;             // gate phase (tid<64)
  const int rb = tid >> 7, rc = tid & 127;            // reduce phase
  const int rgc = ((rc >> 5) << 8) + base + (rc & 31);
  float cReg = 0.f, hReg = 0.f;
  float xwreg = xw[(rb * 256 + (dir ? 255 : 0)) * 1024 + rgc];

  for (int s = 0; s < LSEQ; s++) {
    const int t = dir ? (LSEQ - 1 - s) : s;
    if (s == 0) {
      hsh[tid] = make_float2(0.f, 0.f);
    } else {
      float* p0 = hstep + (s - 1) * 512 + tid;
      float* p1 = p0 + 256;
      float b0 = aload(p0);
      float b1 = aload(p1);
      while (b0 != b0 || b1 != b1) {        // poll until both non-NaN
        if (b0 != b0) b0 = aload(p0);
        if (b1 != b1) b1 = aload(p1);
      }
      hsh[tid] = make_float2(b0, b1);
    }
    __syncthreads();                                   // B
    float a00 = 0.f, a01 = 0.f, a02 = 0.f, a03 = 0.f;
    float a10 = 0.f, a11 = 0.f, a12 = 0.f, a13 = 0.f;
#pragma unroll
    for (int j = 0; j < 32; j++) {
      const float2 h = hsh[k0 + j];
      const float4 u = us[j];
      a00 = fmaf(h.x, u.x, a00); a01 = fmaf(h.x, u.y, a01);
      a02 = fmaf(h.x, u.z, a02); a03 = fmaf(h.x, u.w, a03);
      a10 = fmaf(h.y, u.x, a10); a11 = fmaf(h.y, u.y, a11);
      a12 = fmaf(h.y, u.z, a12); a13 = fmaf(h.y, u.w, a13);
    }
    *(float4*)&psum[ksec][lc0]       = make_float4(a00, a01, a02, a03);
    *(float4*)&psum[ksec][128 + lc0] = make_float4(a10, a11, a12, a13);
    __syncthreads();                                   // C
    {
      float z = xwreg;
#pragma unroll
      for (int ks = 0; ks < 8; ks++) z += psum[ks][rb * 128 + rc];
      zsh[rb * 128 + rc] = z;
    }
    __syncthreads();                                   // D
    if (tid < 64) {
      const float* zr = &zsh[gr * 128];
      const float zi = zr[gj], zf = zr[32 + gj], zg = zr[64 + gj], zo = zr[96 + gj];
      const float cn = sigm(zf) * cReg + sigm(zi) * tanhf(zg);
      const float hn = sigm(zo) * tanhf(cn);
      if (toks[gr * 256 + t] != 0) { cReg = cn; hReg = hn; }
      astore(hstep + s * 512 + gr * 256 + base + gj, hReg);
    }
    // prefetch next step's xw (independent of the data sync)
    const int t2 = dir ? (s < 255 ? 254 - s : 0) : (s < 255 ? s + 1 : 255);
    xwreg = xw[(rb * 256 + t2) * 1024 + rgc];
  }
}

// ---------------- k_uv: u,v = relu(enc@W + b); grid 128, 4 rows/block ----------------
__global__ __launch_bounds__(256) void k_uv(float* __restrict__ ws)
{
  __shared__ float encs[4][512];
  const int tid = threadIdx.x, blk = blockIdx.x;
  for (int i = tid; i < 2048; i += 256) {
    const int rr = i >> 9, h = i & 511;
    const int row = blk * 4 + rr, b = row >> 8, t = row & 255;
    encs[rr][h] = (h < 256)
        ? ws[HF_O + (t * 2 + b) * 256 + h]
        : ws[HB_O + ((255 - t) * 2 + b) * 256 + (h - 256)];
  }
  __syncthreads();
  const float* wp[3]; float bias[3]; int mats[3], cs[3];
#pragma unroll
  for (int g = 0; g < 3; g++) {
    const int colid = tid + (g << 8);
    mats[g] = colid >> 7; cs[g] = colid & 127;
    const int head = mats[g] >> 1, part = mats[g] & 1;
    wp[g]  = ws + HD0 + head * HDS + (part ? 65664 : 0) + cs[g];
    bias[g] = ws[HD0 + head * HDS + (part ? 131200 : 65536) + cs[g]];
  }
  float acc[3][4];
#pragma unroll
  for (int g = 0; g < 3; g++)
#pragma unroll
    for (int rr = 0; rr < 4; rr++) acc[g][rr] = 0.f;
  for (int k = 0; k < 512; k++) {
    const float e0 = encs[0][k], e1 = encs[1][k], e2 = encs[2][k], e3 = encs[3][k];
#pragma unroll
    for (int g = 0; g < 3; g++) {
      const float w = wp[g][k * 128];
      acc[g][0] = fmaf(e0, w, acc[g][0]);
      acc[g][1] = fmaf(e1, w, acc[g][1]);
      acc[g][2] = fmaf(e2, w, acc[g][2]);
      acc[g][3] = fmaf(e3, w, acc[g][3]);
    }
  }
#pragma unroll
  for (int g = 0; g < 3; g++)
#pragma unroll
    for (int rr = 0; rr < 4; rr++) {
      const int row = blk * 4 + rr;
      ws[UV_O + (mats[g] * 512 + row) * 128 + cs[g]] = fmaxf(acc[g][rr] + bias[g], 0.f);
    }
}

// ---------------- k_pq: P=(u@Wuv1+buv)@Wc, Q=(v@Wuv2)@Wc; grid 256, 2 rows ----------------
__global__ __launch_bounds__(128) void k_pq(float* __restrict__ ws)
{
  __shared__ float us[2][6][128];
  __shared__ float ash[2][3][128], qsh[2][3][128];
  const int blk = blockIdx.x, tid = threadIdx.x;
  for (int i = tid; i < 1536; i += 128) {
    const int rr = i / 768, rem = i % 768, mat = rem >> 7, e = rem & 127;
    us[rr][mat][e] = ws[UV_O + (mat * 512 + blk * 2 + rr) * 128 + e];
  }
  __syncthreads();
#pragma unroll
  for (int hd = 0; hd < 3; hd++) {
    const float* W = ws + HD0 + hd * HDS + 131328;
    float a0 = 0.f, a1 = 0.f, q0 = 0.f, q1 = 0.f;
    for (int k = 0; k < 128; k++) {
      const float w1 = W[k * 128 + tid];
      const float w2 = W[(128 + k) * 128 + tid];
      a0 = fmaf(us[0][2 * hd][k], w1, a0);
      a1 = fmaf(us[1][2 * hd][k], w1, a1);
      q0 = fmaf(us[0][2 * hd + 1][k], w2, q0);
      q1 = fmaf(us[1][2 * hd + 1][k], w2, q1);
    }
    const float buv = ws[HD0 + hd * HDS + 164096 + tid];
    ash[0][hd][tid] = a0 + buv; ash[1][hd][tid] = a1 + buv;  // fold buv into P
    qsh[0][hd][tid] = q0;       qsh[1][hd][tid] = q1;
  }
  __syncthreads();
  if (tid < 98) {
    for (int rr = 0; rr < 2; rr++) {
      const int row = blk * 2 + rr;
      const float* src; float* dst; const float* Wc; int o, nout;
      if (tid < 2) {
        Wc = ws + HD0 + 164224; nout = 1; o = 0;
        src = (tid == 0) ? ash[rr][0] : qsh[rr][0];
        dst = ws + ((tid == 0) ? PEH_O : QEH_O) + row;
      } else if (tid < 50) {
        Wc = ws + HD1 + 164224; nout = 24;
        if (tid < 26) { o = tid - 2;  src = ash[rr][1]; dst = ws + PHH_O + row * 24 + o; }
        else          { o = tid - 26; src = qsh[rr][1]; dst = ws + QHH_O + row * 24 + o; }
      } else {
        Wc = ws + HD2 + 164224; nout = 24;
        if (tid < 74) { o = tid - 50; src = ash[rr][2]; dst = ws + PTT_O + row * 24 + o; }
        else          { o = tid - 74; src = qsh[rr][2]; dst = ws + QTT_O + row * 24 + o; }
      }
      float acc = 0.f;
      for (int e = 0; e < 128; e++) acc = fmaf(src[e], Wc[e * nout + o], acc);
      *dst = acc;
    }
  }
}

// ---------------- k_out: out[b,i,j] = act(P[b,j] + Q[b,i] + bc) ----------------
__global__ __launch_bounds__(256) void k_out(const float* __restrict__ ws,
                                             void* __restrict__ outv)
{
  __shared__ float qh[24], qt[24];
  __shared__ float qe_s;
  __shared__ u32 sh[3072], st[3072];
  const bool f32m = ws[DT_O] > 0.5f;
  const int bi = blockIdx.x, b = bi >> 8, i = bi & 255;
  const int j = threadIdx.x;
  if (j < 24)       qh[j] = ws[QHH_O + (b * 256 + i) * 24 + j] + ws[HD1 + 167296 + j];
  else if (j < 48)  qt[j - 24] = ws[QTT_O + (b * 256 + i) * 24 + (j - 24)] + ws[HD2 + 167296 + (j - 24)];
  else if (j == 48) qe_s = ws[QEH_O + b * 256 + i] + ws[HD0 + 167296];
  __syncthreads();
  {
    float v = ws[PEH_O + b * 256 + j] + qe_s;
    v = 1.f / (1.f + __expf(-v));
    if (f32m) ((float*)outv)[(b * 256 + i) * 256 + j] = v;
    else      ((u16*)outv)[(b * 256 + i) * 256 + j] = f2b(v);
  }
  float p[24];
  {
    const float* pp = ws + PHH_O + (b * 256 + j) * 24;
    float mx = -1e30f;
#pragma unroll
    for (int o = 0; o < 24; o++) { p[o] = pp[o] + qh[o]; mx = fmaxf(mx, p[o]); }
    float ssum = 0.f;
#pragma unroll
    for (int o = 0; o < 24; o++) { p[o] = __expf(p[o] - mx); ssum += p[o]; }
    const float inv = 1.f / ssum;
    if (f32m) {
      float* dst = (float*)outv + 131072 + (size_t)(bi * 256 + j) * 24;
#pragma unroll
      for (int m = 0; m < 6; m++)
        ((float4*)dst)[m] = make_float4(p[4*m]*inv, p[4*m+1]*inv, p[4*m+2]*inv, p[4*m+3]*inv);
    } else {
#pragma unroll
      for (int m = 0; m < 12; m++)
        sh[j * 12 + m] = ((u32)f2b(p[2*m+1] * inv) << 16) | (u32)f2b(p[2*m] * inv);
    }
  }
  {
    const float* pp = ws + PTT_O + (b * 256 + j) * 24;
    float mx = -1e30f;
#pragma unroll
    for (int o = 0; o < 24; o++) { p[o] = pp[o] + qt[o]; mx = fmaxf(mx, p[o]); }
    float ssum = 0.f;
#pragma unroll
    for (int o = 0; o < 24; o++) { p[o] = __expf(p[o] - mx); ssum += p[o]; }
    const float inv = 1.f / ssum;
    if (f32m) {
      float* dst = (float*)outv + 3276800 + (size_t)(bi * 256 + j) * 24;
#pragma unroll
      for (int m = 0; m < 6; m++)
        ((float4*)dst)[m] = make_float4(p[4*m]*inv, p[4*m+1]*inv, p[4*m+2]*inv, p[4*m+3]*inv);
    } else {
#pragma unroll
      for (int m = 0; m < 12; m++)
        st[j * 12 + m] = ((u32)f2b(p[2*m+1] * inv) << 16) | (u32)f2b(p[2*m] * inv);
    }
  }
  __syncthreads();
  if (!f32m) {
    u32* outu = (u32*)outv;
    const int baseH = 65536 + bi * 3072;     // eh = elems [0,131072)
    const int baseT = 1638400 + bi * 3072;   // tt starts at elem 3276800
#pragma unroll
    for (int m = 0; m < 12; m++) {
      outu[baseH + j + 256 * m] = sh[j + 256 * m];
      outu[baseT + j + 256 * m] = st[j + 256 * m];
    }
  }
}

extern "C" void kernel_launch(void* const* d_in, const int* in_sizes, int n_in,
                              void* d_out, int out_size, void* d_ws, size_t ws_size,
                              hipStream_t stream) {
  const int* toks = (const int*)d_in[0];
  const int* wrds = (const int*)d_in[1];
  float* ws = (float*)d_ws;

  k_detect<<<dim3(1), dim3(256), 0, stream>>>(d_in[3], ws);

  PtrPack pk;
  // Wf, Uf, bf, Wb, Ub, bb
  pk.p[0] = d_in[5]; pk.p[1] = d_in[6]; pk.p[2] = d_in[7];
  pk.p[3] = d_in[8]; pk.p[4] = d_in[9]; pk.p[5] = d_in[10];
  // per head: uW, ub, vW, vb, uvW, uvb, clsW, clsb
  for (int h = 0; h < 3; h++)
    for (int a = 0; a < 8; a++)
      pk.p[6 + h * 8 + a] = d_in[11 + h * 8 + a];
  k_convert<<<dim3(128, 30), dim3(256), 0, stream>>>(pk, ws);

  k_embed_xw<<<dim3(128), dim3(256), 0, stream>>>(toks, wrds, d_in[3], d_in[4], ws);
  k_lstm<<<dim3(16), dim3(256), 0, stream>>>(toks, ws);
  k_uv<<<dim3(128), dim3(256), 0, stream>>>(ws);
  k_pq<<<dim3(256), dim3(128), 0, stream>>>(ws);
  k_out<<<dim3(512), dim3(256), 0, stream>>>(ws, d_out);
}

// Round 4
// 764.988 us; speedup vs baseline: 1.1342x; 1.0552x over previous
//
#include <hip/hip_runtime.h>
#include <hip/hip_bf16.h>

typedef unsigned short u16;
typedef unsigned int u32;
typedef unsigned long long u64;

#define LSEQ 256

// ---------------- ws float-offsets ----------------
constexpr int XW_F  = 0;        // [b][t][1024] fp32 (x@W + b), fwd
constexpr int XW_B  = 524288;   // bwd
constexpr int HF_O  = 1048576;  // hstep_f [s][k] -> (f32 b0, f32 b1) pairs
constexpr int HB_O  = 1179648;  // hstep_b [s][k] pairs (s = step, t_orig = 255-s)
constexpr int UV_O  = 1310720;  // [mat 0..5][row 0..511][128] relu activations
constexpr int PEH_O = 1703936;  // [512]
constexpr int QEH_O = 1704448;  // [512]
constexpr int PHH_O = 1704960;  // [512][24]
constexpr int QHH_O = 1717248;
constexpr int PTT_O = 1729536;
constexpr int QTT_O = 1741824;
constexpr int DT_O  = 1754128;  // dtype flag as float: 1.0 = fp32 inputs, 0.0 = bf16
// converted-to-fp32 weights:
constexpr int CW_WF = 1754240;  // 262144
constexpr int CW_UF = 2016384;  // 262144
constexpr int CW_BF = 2278528;  // 1024
constexpr int CW_WB = 2279552;  // 262144
constexpr int CW_UB = 2541696;  // 262144
constexpr int CW_BB = 2803840;  // 1024
constexpr int HD0   = 2804864;  // per-head block
constexpr int HDS   = 167424;   // head stride
constexpr int HD1   = HD0 + HDS;
constexpr int HD2   = HD0 + 2 * HDS;
// within-head offsets: uW 0, ub 65536, vW 65664, vb 131200, uvW 131328,
// uvb 164096, clsW 164224, clsb 167296

constexpr u64 SENT64 = 0x7FC000007FC00000ULL;  // (qNaN,qNaN) fp32 pair

__device__ __forceinline__ float b2f(u16 u) {
  u32 x = ((u32)u) << 16; float f;
  __builtin_memcpy(&f, &x, 4); return f;
}
__device__ __forceinline__ u16 f2b(float f) {
  u32 x; __builtin_memcpy(&x, &f, 4);
  u32 r = (x + 0x7fffu + ((x >> 16) & 1u)) >> 16;
  return (u16)r;
}
__device__ __forceinline__ float sigm(float x) {
  return __builtin_amdgcn_rcpf(1.f + __expf(-x));
}
__device__ __forceinline__ float tanh_fast(float x) {
  return 2.f * __builtin_amdgcn_rcpf(1.f + __expf(-2.f * x)) - 1.f;
}
__device__ __forceinline__ u64 aload64(u64* p) {
  return __hip_atomic_load(p, __ATOMIC_RELAXED, __HIP_MEMORY_SCOPE_AGENT);
}
__device__ __forceinline__ void astore64(u64* p, u64 v) {
  __hip_atomic_store(p, v, __ATOMIC_RELAXED, __HIP_MEMORY_SCOPE_AGENT);
}

// ---------------- k_detect: dtype probe ----------------
__global__ __launch_bounds__(256) void k_detect(const void* __restrict__ etab,
                                                float* __restrict__ ws)
{
  __shared__ int cnt;
  const int tid = threadIdx.x;
  if (tid == 0) cnt = 0;
  __syncthreads();
  const u32 w = ((const u32*)etab)[tid];
  // low u16 viewed as bf16: |x| >= 2 <=> bit14 set. fp32 storage: mantissa
  // bit (~uniform) -> ~128/256 hits. bf16 storage: small weight -> 0 hits.
  if (w & 0x4000u) atomicAdd(&cnt, 1);
  __syncthreads();
  if (tid == 0) ws[DT_O] = (cnt >= 16) ? 1.0f : 0.0f;
}

// ---------------- k_convert: normalize all weights to fp32 in ws ----------------
struct PtrPack { const void* p[30]; };

__global__ __launch_bounds__(256) void k_convert(PtrPack pk, float* __restrict__ ws)
{
  const int cnts[30] = {
    262144, 262144, 1024, 262144, 262144, 1024,
    65536, 128, 65536, 128, 32768, 128, 128, 1,
    65536, 128, 65536, 128, 32768, 128, 3072, 24,
    65536, 128, 65536, 128, 32768, 128, 3072, 24};
  const int dsts[30] = {
    CW_WF, CW_UF, CW_BF, CW_WB, CW_UB, CW_BB,
    HD0, HD0 + 65536, HD0 + 65664, HD0 + 131200, HD0 + 131328, HD0 + 164096, HD0 + 164224, HD0 + 167296,
    HD1, HD1 + 65536, HD1 + 65664, HD1 + 131200, HD1 + 131328, HD1 + 164096, HD1 + 164224, HD1 + 167296,
    HD2, HD2 + 65536, HD2 + 65664, HD2 + 131200, HD2 + 131328, HD2 + 164096, HD2 + 164224, HD2 + 167296};
  const int job = blockIdx.y;
  const int n = cnts[job];
  float* dst = ws + dsts[job];
  const void* src = pk.p[job];
  const bool f32m = ws[DT_O] > 0.5f;
  const int tid = threadIdx.x;
  const int idx = blockIdx.x * 256 + tid;
  const int stride = 64 * 256;
  const int n4 = n >> 2;
  if (f32m) {
    const float4* s = (const float4*)src;
    float4* d = (float4*)dst;
    for (int i = idx; i < n4; i += stride) d[i] = s[i];
  } else {
    const ushort4* s = (const ushort4*)src;
    float4* d = (float4*)dst;
    for (int i = idx; i < n4; i += stride) {
      ushort4 v = s[i];
      d[i] = make_float4(b2f(v.x), b2f(v.y), b2f(v.z), b2f(v.w));
    }
  }
  if (blockIdx.x == 0) {
    for (int i = (n4 << 2) + tid; i < n; i += 256)
      dst[i] = f32m ? ((const float*)src)[i] : b2f(((const u16*)src)[i]);
  }
}

// ---------------- k_embed_xw: sentinel-init hstep + embeddings + x@W (+b) ----------------
// grid 64, 8 rows/block
__global__ __launch_bounds__(256) void k_embed_xw(
    const int* __restrict__ toks, const int* __restrict__ wrds,
    const void* __restrict__ etab, const void* __restrict__ wtab,
    float* __restrict__ ws)
{
  __shared__ float xs[8][256];
  const int tid = threadIdx.x, blk = blockIdx.x;
  // sentinel init of hstep (131072 u64 pairs covering HF+HB regions).
  // L2-bypassing atomic stores so no dirty sentinel line can be written back
  // to L3 after real h values land.
  {
    u64* hz = (u64*)(ws + HF_O) + (blk * 256 + tid) * 8;
#pragma unroll
    for (int m = 0; m < 8; m++) astore64(hz + m, SENT64);
  }
  const bool f32m = ws[DT_O] > 0.5f;
  for (int rr = 0; rr < 8; rr++) {
    const int row = blk * 8 + rr;
    const int id = toks[row], wid = wrds[row];
    float v;
    if (f32m) {
      v = (tid < 128) ? ((const float*)etab)[id * 128 + tid]
                      : ((const float*)wtab)[wid * 128 + (tid - 128)];
    } else {
      v = (tid < 128) ? b2f(((const u16*)etab)[id * 128 + tid])
                      : b2f(((const u16*)wtab)[wid * 128 + (tid - 128)]);
    }
    xs[rr][tid] = v;
  }
  __syncthreads();
  float aF[8][4], aB[8][4];
#pragma unroll
  for (int rr = 0; rr < 8; rr++)
#pragma unroll
    for (int c = 0; c < 4; c++) { aF[rr][c] = 0.f; aB[rr][c] = 0.f; }
  const float2* Wf2 = (const float2*)(ws + CW_WF);
  const float2* Wb2 = (const float2*)(ws + CW_WB);
  for (int k = 0; k < 256; k++) {
    const float2 wfa = Wf2[k * 512 + tid];
    const float2 wfb = Wf2[k * 512 + 256 + tid];
    const float2 wba = Wb2[k * 512 + tid];
    const float2 wbb = Wb2[k * 512 + 256 + tid];
#pragma unroll
    for (int rr = 0; rr < 8; rr++) {
      const float x = xs[rr][k];
      aF[rr][0] = fmaf(x, wfa.x, aF[rr][0]); aF[rr][1] = fmaf(x, wfa.y, aF[rr][1]);
      aF[rr][2] = fmaf(x, wfb.x, aF[rr][2]); aF[rr][3] = fmaf(x, wfb.y, aF[rr][3]);
      aB[rr][0] = fmaf(x, wba.x, aB[rr][0]); aB[rr][1] = fmaf(x, wba.y, aB[rr][1]);
      aB[rr][2] = fmaf(x, wbb.x, aB[rr][2]); aB[rr][3] = fmaf(x, wbb.y, aB[rr][3]);
    }
  }
  const int c0 = 2 * tid, c2 = 512 + 2 * tid;
#pragma unroll
  for (int rr = 0; rr < 8; rr++) {
    const int row = blk * 8 + rr;
    float* of = ws + XW_F + row * 1024;
    of[c0]   = aF[rr][0] + ws[CW_BF + c0];
    of[c0+1] = aF[rr][1] + ws[CW_BF + c0 + 1];
    of[c2]   = aF[rr][2] + ws[CW_BF + c2];
    of[c2+1] = aF[rr][3] + ws[CW_BF + c2 + 1];
    float* ob = ws + XW_B + row * 1024;
    ob[c0]   = aB[rr][0] + ws[CW_BB + c0];
    ob[c0+1] = aB[rr][1] + ws[CW_BB + c0 + 1];
    ob[c2]   = aB[rr][2] + ws[CW_BB + c2];
    ob[c2+1] = aB[rr][3] + ws[CW_BB + c2 + 1];
  }
}

// ---------------- k_lstm: recurrence, U in VGPRs, 64-bit NaN-sentinel sync ----------------
// 16 WGs: 8 per direction, each owns 32 hidden units (128 gate-cols).
// h[b0],h[b1] packed in one u64 -> SINGLE agent-atomic load per poll word.
// Remote poll (threads 32..255) overlaps with wave-0 gate compute; own chunk
// enters next step's LDS buffer directly.
__global__ __launch_bounds__(256, 1) void k_lstm(
    const int* __restrict__ toks, float* __restrict__ ws)
{
  __shared__ float2 hsh[2][256];   // double-buffered (b0,b1) per k
  __shared__ float psum[8][256];   // [ksec][b*128 + c]
  __shared__ float zsh[256];       // [b*128 + c]
  __shared__ int msk[512];         // token mask, [b][t]
  const int tid = threadIdx.x;
  const int dir = blockIdx.x >> 3, chunk = blockIdx.x & 7, base = chunk * 32;
  const int q = tid & 31, ksec = tid >> 5, k0 = ksec * 32;
  u64* h64 = (u64*)(ws + (dir ? HB_O : HF_O));
  const float* xw = ws + (dir ? XW_B : XW_F);
  const float* Ubase = ws + (dir ? CW_UB : CW_UF);

  const int lc0 = 4 * q;
  const int gc0 = ((lc0 >> 5) << 8) + base + (lc0 & 31);
  float4 us[32];
#pragma unroll
  for (int j = 0; j < 32; j++)
    us[j] = *(const float4*)(Ubase + (k0 + j) * 1024 + gc0);

  const int gu = tid & 31, bsel = tid >> 5;     // gate roles (tid<64)
  const int rb = tid >> 7, rc = tid & 127;      // reduce roles
  const int rgc = ((rc >> 5) << 8) + base + (rc & 31);
  const int widx = tid - 32;                    // poll roles (tid>=32)
  const int pkk = widx + (widx >= base ? 32 : 0);

  float cReg = 0.f, hReg = 0.f;
  float xwreg = xw[(rb * 256 + (dir ? 255 : 0)) * 1024 + rgc];

  hsh[0][tid] = make_float2(0.f, 0.f);
  msk[tid] = toks[tid];
  msk[tid + 256] = toks[tid + 256];
  __syncthreads();

  for (int s = 0; s < LSEQ; s++) {
    const int par = s & 1, npar = par ^ 1;
    const int t = dir ? (255 - s) : s;
    // ---- h @ U partials (own ksec slice, 4 cols, both batches) ----
    float a00 = 0.f, a01 = 0.f, a02 = 0.f, a03 = 0.f;
    float a10 = 0.f, a11 = 0.f, a12 = 0.f, a13 = 0.f;
#pragma unroll
    for (int j = 0; j < 32; j++) {
      const float2 h = hsh[par][k0 + j];
      const float4 uu = us[j];
      a00 = fmaf(h.x, uu.x, a00); a01 = fmaf(h.x, uu.y, a01);
      a02 = fmaf(h.x, uu.z, a02); a03 = fmaf(h.x, uu.w, a03);
      a10 = fmaf(h.y, uu.x, a10); a11 = fmaf(h.y, uu.y, a11);
      a12 = fmaf(h.y, uu.z, a12); a13 = fmaf(h.y, uu.w, a13);
    }
    *(float4*)&psum[ksec][lc0]       = make_float4(a00, a01, a02, a03);
    *(float4*)&psum[ksec][128 + lc0] = make_float4(a10, a11, a12, a13);
    __syncthreads();                                   // C
    // ---- reduce across ksec + xw ----
    {
      float z = xwreg;
#pragma unroll
      for (int ks = 0; ks < 8; ks++) z += psum[ks][rb * 128 + rc];
      zsh[rb * 128 + rc] = z;
    }
    // prefetch next step's xw (consumed next reduce phase)
    const int t2 = dir ? (s < 255 ? 254 - s : 255) : (s < 255 ? s + 1 : 0);
    xwreg = xw[(rb * 256 + t2) * 1024 + rgc];
    __syncthreads();                                   // D
    // ---- gates (wave 0) ----
    if (tid < 64) {
      const float* zr = &zsh[bsel * 128];
      const float zi = zr[gu], zf = zr[32 + gu], zg = zr[64 + gu], zo = zr[96 + gu];
      const float cn = sigm(zf) * cReg + sigm(zi) * tanh_fast(zg);
      const float hn = sigm(zo) * tanh_fast(cn);
      if (msk[bsel * 256 + t] != 0) { cReg = cn; hReg = hn; }
      const float hb1 = __shfl_xor(hReg, 32);  // lanes<32 receive batch-1 h
      if (tid < 32) {
        const float2 fv = make_float2(hReg, hb1);
        hsh[npar][base + gu] = fv;             // own chunk -> LDS directly
        u64 pv; __builtin_memcpy(&pv, &fv, 8);
        astore64(h64 + s * 256 + base + gu, pv);
      }
    }
    // ---- remote poll (threads 32..255), overlapped with gate phase ----
    if (tid >= 32 && s < 255) {
      u64* p = h64 + s * 256 + pkk;
      u64 v = aload64(p);
      while (v == SENT64) v = aload64(p);
      float2 hv; __builtin_memcpy(&hv, &v, 8);
      hsh[npar][pkk] = hv;
    }
    __syncthreads();                                   // A
  }
}

// ---------------- k_uv: u,v = relu(enc@W + b); grid 64, 8 rows/block ----------------
__global__ __launch_bounds__(256) void k_uv(float* __restrict__ ws)
{
  __shared__ float encs[8][512];
  const int tid = threadIdx.x, blk = blockIdx.x;
  for (int i = tid; i < 4096; i += 256) {
    const int rr = i >> 9, h = i & 511;
    const int row = blk * 8 + rr, b = row >> 8, t = row & 255;
    encs[rr][h] = (h < 256)
        ? ws[HF_O + t * 512 + h * 2 + b]
        : ws[HB_O + (255 - t) * 512 + (h - 256) * 2 + b];
  }
  __syncthreads();
  const float* wp[3]; float bias[3]; int mats[3], cs[3];
#pragma unroll
  for (int g = 0; g < 3; g++) {
    const int colid = tid + (g << 8);
    mats[g] = colid >> 7; cs[g] = colid & 127;
    const int head = mats[g] >> 1, part = mats[g] & 1;
    wp[g]  = ws + HD0 + head * HDS + (part ? 65664 : 0) + cs[g];
    bias[g] = ws[HD0 + head * HDS + (part ? 131200 : 65536) + cs[g]];
  }
  float acc[3][8];
#pragma unroll
  for (int g = 0; g < 3; g++)
#pragma unroll
    for (int rr = 0; rr < 8; rr++) acc[g][rr] = 0.f;
  for (int k = 0; k < 512; k++) {
#pragma unroll
    for (int g = 0; g < 3; g++) {
      const float w = wp[g][k * 128];
#pragma unroll
      for (int rr = 0; rr < 8; rr++)
        acc[g][rr] = fmaf(encs[rr][k], w, acc[g][rr]);
    }
  }
#pragma unroll
  for (int g = 0; g < 3; g++)
#pragma unroll
    for (int rr = 0; rr < 8; rr++) {
      const int row = blk * 8 + rr;
      ws[UV_O + (mats[g] * 512 + row) * 128 + cs[g]] = fmaxf(acc[g][rr] + bias[g], 0.f);
    }
}

// ---------------- k_pq: P=(u@Wuv1+buv)@Wc, Q=(v@Wuv2)@Wc; grid 128, 4 rows ----------------
__global__ __launch_bounds__(128) void k_pq(float* __restrict__ ws)
{
  __shared__ float us[4][6][128];
  __shared__ float ash[4][3][128], qsh[4][3][128];
  const int blk = blockIdx.x, tid = threadIdx.x;
  for (int i = tid; i < 3072; i += 128) {
    const int rr = i / 768, rem = i % 768, mat = rem >> 7, e = rem & 127;
    us[rr][mat][e] = ws[UV_O + (mat * 512 + blk * 4 + rr) * 128 + e];
  }
  __syncthreads();
#pragma unroll
  for (int hd = 0; hd < 3; hd++) {
    const float* W = ws + HD0 + hd * HDS + 131328;
    float av[4] = {0.f, 0.f, 0.f, 0.f}, qv[4] = {0.f, 0.f, 0.f, 0.f};
    for (int k = 0; k < 128; k++) {
      const float w1 = W[k * 128 + tid];
      const float w2 = W[(128 + k) * 128 + tid];
#pragma unroll
      for (int rr = 0; rr < 4; rr++) {
        av[rr] = fmaf(us[rr][2 * hd][k], w1, av[rr]);
        qv[rr] = fmaf(us[rr][2 * hd + 1][k], w2, qv[rr]);
      }
    }
    const float buv = ws[HD0 + hd * HDS + 164096 + tid];
#pragma unroll
    for (int rr = 0; rr < 4; rr++) {
      ash[rr][hd][tid] = av[rr] + buv;  // fold buv into P-side
      qsh[rr][hd][tid] = qv[rr];
    }
  }
  __syncthreads();
  if (tid < 98) {
    for (int rr = 0; rr < 4; rr++) {
      const int row = blk * 4 + rr;
      const float* src; float* dst; const float* Wc; int o, nout;
      if (tid < 2) {
        Wc = ws + HD0 + 164224; nout = 1; o = 0;
        src = (tid == 0) ? ash[rr][0] : qsh[rr][0];
        dst = ws + ((tid == 0) ? PEH_O : QEH_O) + row;
      } else if (tid < 50) {
        Wc = ws + HD1 + 164224; nout = 24;
        if (tid < 26) { o = tid - 2;  src = ash[rr][1]; dst = ws + PHH_O + row * 24 + o; }
        else          { o = tid - 26; src = qsh[rr][1]; dst = ws + QHH_O + row * 24 + o; }
      } else {
        Wc = ws + HD2 + 164224; nout = 24;
        if (tid < 74) { o = tid - 50; src = ash[rr][2]; dst = ws + PTT_O + row * 24 + o; }
        else          { o = tid - 74; src = qsh[rr][2]; dst = ws + QTT_O + row * 24 + o; }
      }
      float acc = 0.f;
      for (int e = 0; e < 128; e++) acc = fmaf(src[e], Wc[e * nout + o], acc);
      *dst = acc;
    }
  }
}

// ---------------- k_out: out[b,i,j] = act(P[b,j] + Q[b,i] + bc) ----------------
__global__ __launch_bounds__(256) void k_out(const float* __restrict__ ws,
                                             void* __restrict__ outv)
{
  __shared__ float qh[24], qt[24];
  __shared__ float qe_s;
  __shared__ u32 sh[3072], st[3072];
  const bool f32m = ws[DT_O] > 0.5f;
  const int bi = blockIdx.x, b = bi >> 8, i = bi & 255;
  const int j = threadIdx.x;
  if (j < 24)       qh[j] = ws[QHH_O + (b * 256 + i) * 24 + j] + ws[HD1 + 167296 + j];
  else if (j < 48)  qt[j - 24] = ws[QTT_O + (b * 256 + i) * 24 + (j - 24)] + ws[HD2 + 167296 + (j - 24)];
  else if (j == 48) qe_s = ws[QEH_O + b * 256 + i] + ws[HD0 + 167296];
  __syncthreads();
  {
    float v = ws[PEH_O + b * 256 + j] + qe_s;
    v = 1.f / (1.f + __expf(-v));
    if (f32m) ((float*)outv)[(b * 256 + i) * 256 + j] = v;
    else      ((u16*)outv)[(b * 256 + i) * 256 + j] = f2b(v);
  }
  float p[24];
  {
    const float* pp = ws + PHH_O + (b * 256 + j) * 24;
    float mx = -1e30f;
#pragma unroll
    for (int o = 0; o < 24; o++) { p[o] = pp[o] + qh[o]; mx = fmaxf(mx, p[o]); }
    float ssum = 0.f;
#pragma unroll
    for (int o = 0; o < 24; o++) { p[o] = __expf(p[o] - mx); ssum += p[o]; }
    const float inv = 1.f / ssum;
    if (f32m) {
      float* dst = (float*)outv + 131072 + (size_t)(bi * 256 + j) * 24;
#pragma unroll
      for (int m = 0; m < 6; m++)
        ((float4*)dst)[m] = make_float4(p[4*m]*inv, p[4*m+1]*inv, p[4*m+2]*inv, p[4*m+3]*inv);
    } else {
#pragma unroll
      for (int m = 0; m < 12; m++)
        sh[j * 12 + m] = ((u32)f2b(p[2*m+1] * inv) << 16) | (u32)f2b(p[2*m] * inv);
    }
  }
  {
    const float* pp = ws + PTT_O + (b * 256 + j) * 24;
    float mx = -1e30f;
#pragma unroll
    for (int o = 0; o < 24; o++) { p[o] = pp[o] + qt[o]; mx = fmaxf(mx, p[o]); }
    float ssum = 0.f;
#pragma unroll
    for (int o = 0; o < 24; o++) { p[o] = __expf(p[o] - mx); ssum += p[o]; }
    const float inv = 1.f / ssum;
    if (f32m) {
      float* dst = (float*)outv + 3276800 + (size_t)(bi * 256 + j) * 24;
#pragma unroll
      for (int m = 0; m < 6; m++)
        ((float4*)dst)[m] = make_float4(p[4*m]*inv, p[4*m+1]*inv, p[4*m+2]*inv, p[4*m+3]*inv);
    } else {
#pragma unroll
      for (int m = 0; m < 12; m++)
        st[j * 12 + m] = ((u32)f2b(p[2*m+1] * inv) << 16) | (u32)f2b(p[2*m] * inv);
    }
  }
  __syncthreads();
  if (!f32m) {
    u32* outu = (u32*)outv;
    const int baseH = 65536 + bi * 3072;     // eh = elems [0,131072)
    const int baseT = 1638400 + bi * 3072;   // tt starts at elem 3276800
#pragma unroll
    for (int m = 0; m < 12; m++) {
      outu[baseH + j + 256 * m] = sh[j + 256 * m];
      outu[baseT + j + 256 * m] = st[j + 256 * m];
    }
  }
}

extern "C" void kernel_launch(void* const* d_in, const int* in_sizes, int n_in,
                              void* d_out, int out_size, void* d_ws, size_t ws_size,
                              hipStream_t stream) {
  const int* toks = (const int*)d_in[0];
  const int* wrds = (const int*)d_in[1];
  float* ws = (float*)d_ws;

  k_detect<<<dim3(1), dim3(256), 0, stream>>>(d_in[3], ws);

  PtrPack pk;
  // Wf, Uf, bf, Wb, Ub, bb
  pk.p[0] = d_in[5]; pk.p[1] = d_in[6]; pk.p[2] = d_in[7];
  pk.p[3] = d_in[8]; pk.p[4] = d_in[9]; pk.p[5] = d_in[10];
  // per head: uW, ub, vW, vb, uvW, uvb, clsW, clsb
  for (int h = 0; h < 3; h++)
    for (int a = 0; a < 8; a++)
      pk.p[6 + h * 8 + a] = d_in[11 + h * 8 + a];
  k_convert<<<dim3(64, 30), dim3(256), 0, stream>>>(pk, ws);

  k_embed_xw<<<dim3(64), dim3(256), 0, stream>>>(toks, wrds, d_in[3], d_in[4], ws);
  k_lstm<<<dim3(16), dim3(256), 0, stream>>>(toks, ws);
  k_uv<<<dim3(64), dim3(256), 0, stream>>>(ws);
  k_pq<<<dim3(128), dim3(128), 0, stream>>>(ws);
  k_out<<<dim3(512), dim3(256), 0, stream>>>(ws, d_out);
}